// Round 17
// baseline (53.489 us; speedup 1.0000x reference)
//
#include <hip/hip_runtime.h>

#define NE 8               // experts
#define H4 512             // float4 per token row (2048 floats)
#define NTOK 16384         // 4 * 4096 tokens
#define TPW 4              // tokens per wave (full K per wave)
#define TPB 16             // tokens per block (4 independent waves)
#define NBLK_A (NTOK / TPB)  // 1024 blocks
#define NBLK_R 64          // aux-reduce blocks (16384 / 256)
#define AUX_COEF 0.01f

// ws layout (floats): qbuf[NTOK*NE] | ws2[NBLK_R*16] | cnt (1 uint)
#define WS2_OFF (NTOK * NE)
#define CNT_OFF (WS2_OFF + NBLK_R * 16)

typedef float f4v __attribute__((ext_vector_type(4)));

// Kernel A: R16's proven streaming loop + logit butterfly, then the CHEAP
// tail only: per-lane softmax + top-2 (uniform, no extra cross-lane ops,
// no aux butterfly — that was R15's mistake). Lanes 0-3 write outputs and
// router-probs. No LDS, no barriers, no part[] round-trip, no kernel B.
__global__ __launch_bounds__(256, 4)
void router_main(const float* __restrict__ hs, const float* __restrict__ gw,
                 float* __restrict__ out, float* __restrict__ qbuf)
{
    const int tid  = threadIdx.x;
    const int wave = tid >> 6, lane = tid & 63;
    const int tok0 = blockIdx.x * TPB + wave * TPW;

    const f4v* __restrict__ hs4 = (const f4v*)hs;
    const f4v* __restrict__ gw4 = (const f4v*)gw;

    float acc[TPW][NE];
    #pragma unroll
    for (int r = 0; r < TPW; ++r)
        #pragma unroll
        for (int e = 0; e < NE; ++e) acc[r][e] = 0.f;

    #pragma unroll
    for (int it = 0; it < 8; ++it) {
        const int col = it * 64 + lane;
        f4v h[TPW];
        #pragma unroll
        for (int r = 0; r < TPW; ++r)
            h[r] = hs4[(size_t)(tok0 + r) * H4 + col];
        f4v g[NE];
        #pragma unroll
        for (int e = 0; e < NE; ++e) g[e] = gw4[e * H4 + col];
        #pragma unroll
        for (int r = 0; r < TPW; ++r)
            #pragma unroll
            for (int e = 0; e < NE; ++e)
                acc[r][e] += h[r].x * g[e].x + h[r].y * g[e].y
                           + h[r].z * g[e].z + h[r].w * g[e].w;
    }

    // butterfly: every lane gets the full dot for all 32 (r,e)
    #pragma unroll
    for (int r = 0; r < TPW; ++r)
        #pragma unroll
        for (int e = 0; e < NE; ++e) {
            float v = acc[r][e];
            #pragma unroll
            for (int s = 32; s > 0; s >>= 1) v += __shfl_xor(v, s, 64);
            acc[r][e] = v;
        }

    // lane (mod 4) picks its token — static indexing only
    const int ls = lane & 3;
    float lg[NE];
    #pragma unroll
    for (int e = 0; e < NE; ++e)
        lg[e] = (ls == 0) ? acc[0][e] : (ls == 1) ? acc[1][e]
              : (ls == 2) ? acc[2][e] : acc[3][e];

    float m = lg[0];
    #pragma unroll
    for (int e = 1; e < NE; ++e) m = fmaxf(m, lg[e]);
    float p[NE];
    float s = 0.f;
    #pragma unroll
    for (int e = 0; e < NE; ++e) { p[e] = __expf(lg[e] - m); s += p[e]; }
    const float inv = 1.f / s;

    // top-2 on probs; strict '>' keeps lowest index on ties (lax.top_k order)
    float v0 = -1.f; int i0 = 0;
    #pragma unroll
    for (int e = 0; e < NE; ++e) { if (p[e] > v0) { v0 = p[e]; i0 = e; } }
    float v1 = -1.f; int i1 = 0;
    #pragma unroll
    for (int e = 0; e < NE; ++e) { if (e != i0 && p[e] > v1) { v1 = p[e]; i1 = e; } }

    // lanes 0-3 write outputs + router-probs for their token (ls == lane)
    if (lane < TPW) {
        const int tok = tok0 + ls;
        float2* __restrict__ o2 = (float2*)out;
        const float wsum = v0 + v1;
        o2[tok]        = make_float2(v0 / wsum, v1 / wsum);
        o2[NTOK + tok] = make_float2((float)i0, (float)i1);
        float4* __restrict__ qb4 = (float4*)qbuf;
        qb4[tok * 2]     = make_float4(p[0] * inv, p[1] * inv,
                                       p[2] * inv, p[3] * inv);
        qb4[tok * 2 + 1] = make_float4(p[4] * inv, p[5] * inv,
                                       p[6] * inv, p[7] * inv);
    }
}

// Aux kernel (single launch, last-block-done): each of 64 blocks reduces
// 256 tokens' router-probs + top-2 counts to a 16-float partial; the last
// block to finish folds the 64 partials (fixed order -> deterministic)
// and writes the aux scalar.
__global__ __launch_bounds__(256)
void router_aux(const float* __restrict__ qbuf, const float* __restrict__ out,
                float* __restrict__ ws2, unsigned int* __restrict__ cnt,
                float* __restrict__ outw)
{
    __shared__ float red[4][16];
    __shared__ int isLast;
    const int tid = threadIdx.x;
    const int t   = blockIdx.x * 256 + tid;      // token

    const float4* __restrict__ q4 = (const float4*)qbuf;
    const float4 a = q4[(size_t)t * 2], b = q4[(size_t)t * 2 + 1];
    const float2* __restrict__ ix2 = (const float2*)(out + 2 * NTOK);
    const float2 ix = ix2[t];
    const int i0 = (int)ix.x, i1 = (int)ix.y;

    float v[16];
    v[0]=a.x; v[1]=a.y; v[2]=a.z; v[3]=a.w;
    v[4]=b.x; v[5]=b.y; v[6]=b.z; v[7]=b.w;
    #pragma unroll
    for (int e = 0; e < NE; ++e)
        v[NE + e] = ((i0 == e) ? 1.f : 0.f) + ((i1 == e) ? 1.f : 0.f);

    #pragma unroll
    for (int e = 0; e < 16; ++e) {
        #pragma unroll
        for (int sh = 32; sh > 0; sh >>= 1) v[e] += __shfl_xor(v[e], sh, 64);
    }

    const int wave = tid >> 6, lane = tid & 63;
    if (lane == 0) {
        #pragma unroll
        for (int e = 0; e < 16; ++e) red[wave][e] = v[e];
    }
    __syncthreads();
    if (tid < 16)
        ws2[blockIdx.x * 16 + tid] =
            red[0][tid] + red[1][tid] + red[2][tid] + red[3][tid];

    __threadfence();
    __syncthreads();
    if (tid == 0) {
        const unsigned int old = atomicAdd(cnt, 1u);
        isLast = (old == NBLK_R - 1) ? 1 : 0;
    }
    __syncthreads();

    if (isLast) {
        __threadfence();
        if (tid < 16) {
            float t2 = 0.f;
            #pragma unroll 8
            for (int r = 0; r < NBLK_R; ++r) t2 += ws2[r * 16 + tid];
            red[0][tid] = t2;
        }
        __syncthreads();
        if (tid == 0) {
            float s2 = 0.f;
            #pragma unroll
            for (int e2 = 0; e2 < NE; ++e2) {
                const float ef = red[0][NE + e2] / (float)(NTOK * 2);
                const float rf = red[0][e2] / (float)NTOK;
                s2 += ef * rf;
            }
            outw[4 * NTOK] = (float)NE * s2 * AUX_COEF;
        }
    }
}

extern "C" void kernel_launch(void* const* d_in, const int* in_sizes, int n_in,
                              void* d_out, int out_size, void* d_ws, size_t ws_size,
                              hipStream_t stream)
{
    const float* hs = (const float*)d_in[0];   // [4,4096,2048] f32
    const float* gw = (const float*)d_in[1];   // [8,2048] f32
    float* out  = (float*)d_out;               // 32768 rw | 32768 idx | 1 aux
    float* qbuf = (float*)d_ws;                // [16384][8] router probs
    float* ws2  = (float*)d_ws + WS2_OFF;      // [64][16] partials
    unsigned int* cnt = (unsigned int*)((float*)d_ws + CNT_OFF);

    hipMemsetAsync(cnt, 0, sizeof(unsigned int), stream);
    hipLaunchKernelGGL(router_main, dim3(NBLK_A), dim3(256), 0, stream,
                       hs, gw, out, qbuf);
    hipLaunchKernelGGL(router_aux, dim3(NBLK_R), dim3(256), 0, stream,
                       qbuf, out, ws2, cnt, out);
}